// Round 1
// baseline (63.082 us; speedup 1.0000x reference)
//
#include <hip/hip_runtime.h>

#define NQ 6
#define NL 6

// One wave (64 lanes) simulates one sample; lane k holds complex amplitude k.
// Qubit w <-> bit (NQ-1-w) of the lane index.
__global__ __launch_bounds__(256) void qsim_kernel(
    const float* __restrict__ x,
    const float* __restrict__ w,
    float* __restrict__ out,
    int batch)
{
    const int wave = (int)((blockIdx.x * blockDim.x + threadIdx.x) >> 6);
    const int lane = (int)(threadIdx.x & 63);
    if (wave >= batch) return;
    const int b = wave;

    const float TWO_PI_F = 6.2831853f;

    // ---- encode angles (wave-uniform) ----
    const float x0 = x[b * 3 + 0];
    const float x1 = x[b * 3 + 1];
    const float x2 = x[b * 3 + 2];
    const float theta = acosf(fminf(1.f, fmaxf(-1.f, x2)));
    const float phi = fmodf(atan2f(x1, x0) + TWO_PI_F, TWO_PI_F);

    float st, ct, sp, cp;
    __sincosf(theta * 0.5f, &st, &ct);
    __sincosf(phi * 0.5f, &sp, &cp);

    // |0...0>
    float re = (lane == 0) ? 1.f : 0.f;
    float im = 0.f;

    // ---- encoding layer: RY(theta) then RZ(phi) on each qubit ----
    #pragma unroll
    for (int q = 0; q < NQ; ++q) {
        const int mask = 1 << (NQ - 1 - q);
        // RY
        float ore = __shfl_xor(re, mask);
        float oim = __shfl_xor(im, mask);
        const float sg = (lane & mask) ? st : -st;
        re = ct * re + sg * ore;
        im = ct * im + sg * oim;
        // RZ: bit0 -> exp(-i phi/2), bit1 -> exp(+i phi/2)
        const float s = (lane & mask) ? sp : -sp;
        const float nre = re * cp - im * s;
        const float nim = re * s + im * cp;
        re = nre; im = nim;
    }

    // ---- variational layers ----
    const float* wp = w + (size_t)b * (NL * 2 * NQ);
    for (int l = 0; l < NL; ++l) {
        #pragma unroll
        for (int q = 0; q < NQ; ++q) {
            const int mask = 1 << (NQ - 1 - q);
            const float az = wp[l * 12 + 2 * q];
            const float ay = wp[l * 12 + 2 * q + 1];
            float sz, cz, sy, cy;
            __sincosf(az * 0.5f, &sz, &cz);
            __sincosf(ay * 0.5f, &sy, &cy);
            // RZ first
            {
                const float s = (lane & mask) ? sz : -sz;
                const float nre = re * cz - im * s;
                const float nim = re * s + im * cz;
                re = nre; im = nim;
            }
            // then RY
            {
                float ore = __shfl_xor(re, mask);
                float oim = __shfl_xor(im, mask);
                const float sg = (lane & mask) ? sy : -sy;
                re = cy * re + sg * ore;
                im = cy * im + sg * oim;
            }
        }
        // CNOT chain i -> i+1
        #pragma unroll
        for (int c = 0; c < NQ - 1; ++c) {
            const int cmask = 1 << (NQ - 1 - c);
            const int tmask = 1 << (NQ - 2 - c);
            float tre = __shfl_xor(re, tmask);
            float tim = __shfl_xor(im, tmask);
            if (lane & cmask) { re = tre; im = tim; }
        }
        // CNOT(NQ-1, 0)
        {
            const int cmask = 1;
            const int tmask = 1 << (NQ - 1);
            float tre = __shfl_xor(re, tmask);
            float tim = __shfl_xor(im, tmask);
            if (lane & cmask) { re = tre; im = tim; }
        }
    }

    // ---- measurement: probs -> 6 Pauli-Z expectations via FWHT ----
    float v = re * re + im * im;
    #pragma unroll
    for (int m = 0; m < NQ; ++m) {
        const int mask = 1 << m;
        const float o = __shfl_xor(v, mask);
        v = (lane & mask) ? (o - v) : (v + o);
    }
    // lane e holds WHT[e] = sum_k (-1)^{popcount(e&k)} prob[k];
    // exp_val[q] = WHT[1 << (NQ-1-q)]. Gather to lanes 0..5 for coalesced store.
    const int src = (lane < NQ) ? (1 << (NQ - 1 - lane)) : 0;
    const float ev = __shfl(v, src);
    if (lane < NQ) {
        out[(size_t)b * NQ + lane] = 1.f / (1.f + __expf(-ev));
    }
}

extern "C" void kernel_launch(void* const* d_in, const int* in_sizes, int n_in,
                              void* d_out, int out_size, void* d_ws, size_t ws_size,
                              hipStream_t stream) {
    const float* x = (const float*)d_in[0];
    const float* w = (const float*)d_in[1];
    float* out = (float*)d_out;
    const int batch = in_sizes[0] / 3;  // B = 32768

    const int threads = 256;                       // 4 waves/block
    const int waves_per_block = threads / 64;
    const int blocks = (batch + waves_per_block - 1) / waves_per_block;
    qsim_kernel<<<blocks, threads, 0, stream>>>(x, w, out, batch);
}

// Round 2
// 49.858 us; speedup vs baseline: 1.2652x; 1.2652x over previous
//
#include <hip/hip_runtime.h>

#define NQ 6
#define NL 6

// One wave (64 lanes) per sample; lane k holds complex amplitude k.
// Qubit q <-> bit (5-q) of the lane index.
//
// R2 changes vs R1:
//  - 72 layer-angle sincos computed LANE-PARALLEL (2 sincos issues total),
//    stored as (cos,sin) pairs in a per-wave LDS table, broadcast per gate
//    via wave-uniform ds_read_b64 (removes ~72 wave-wide sincos per sample).
//  - encode trig via half-angle sqrt identities (no acos/atan2/fmod/sincos).
//    2pi phase ambiguity is a global phase -> cancels in |psi|^2.
//  - per-layer 6-CNOT block fused into ONE lane permutation (GF(2)-linear),
//    applied with a single __shfl (ds_bpermute) per component.
__global__ __launch_bounds__(256) void qsim_kernel(
    const float* __restrict__ x,
    const float* __restrict__ w,
    float* __restrict__ out,
    int batch)
{
    const int tid  = blockIdx.x * blockDim.x + threadIdx.x;
    const int lane = threadIdx.x & 63;
    const int b    = tid >> 6;
    if (b >= batch) return;               // wave-uniform (exact grid anyway)

    // per-wave trig table: 72 (cos,sin) pairs = 144 floats
    __shared__ float tbl[4][144];
    float* T = tbl[threadIdx.x >> 6];

    // ---- lane-parallel trig for the 72 layer angles ----
    const float* wp = w + (size_t)b * (2 * NQ * NL);
    {
        const float a0 = wp[lane];        // angles 0..63
        float s0, c0;
        __sincosf(a0 * 0.5f, &s0, &c0);
        T[2 * lane]     = c0;
        T[2 * lane + 1] = s0;
        if (lane < 8) {
            const float a1 = wp[64 + lane];  // angles 64..71
            float s1, c1;
            __sincosf(a1 * 0.5f, &s1, &c1);
            T[128 + 2 * lane]     = c1;
            T[128 + 2 * lane + 1] = s1;
        }
    }

    // ---- encode angles via half-angle identities (no transcendentals) ----
    const float x0 = x[b * 3 + 0];
    const float x1 = x[b * 3 + 1];
    const float x2 = x[b * 3 + 2];
    const float z  = fminf(1.f, fmaxf(-1.f, x2));
    const float ct = sqrtf(0.5f * (1.f + z));           // cos(theta/2)
    const float st = sqrtf(0.5f * (1.f - z));           // sin(theta/2)
    const float r  = sqrtf(x0 * x0 + x1 * x1) + 1e-30f;
    const float cphi = x0 / r;                          // cos(phi)
    const float cp = sqrtf(fmaxf(0.f, 0.5f * (1.f + cphi)));  // cos(phi/2)
    float sp       = sqrtf(fmaxf(0.f, 0.5f * (1.f - cphi)));  // |sin(phi/2)|
    sp = (x1 < 0.f) ? -sp : sp;   // sign(phi/2)=sign(x1); 2pi wrap = global phase

    // ---- fused CNOT-block source lane (compose 6 CNOTs, reverse order) ----
    int src = lane;
    src ^= (src & 1)  ? 32 : 0;   // CNOT(5,0)  (last applied)
    src ^= (src & 2)  ? 1  : 0;   // CNOT(4,5)
    src ^= (src & 4)  ? 2  : 0;   // CNOT(3,4)
    src ^= (src & 8)  ? 4  : 0;   // CNOT(2,3)
    src ^= (src & 16) ? 8  : 0;   // CNOT(1,2)
    src ^= (src & 32) ? 16 : 0;   // CNOT(0,1)  (first applied)

    // ---- |0...0> ----
    float re = (lane == 0) ? 1.f : 0.f;
    float im = 0.f;

    // ---- encoding layer: RY(theta) then RZ(phi) on each qubit ----
    #pragma unroll
    for (int q = 0; q < NQ; ++q) {
        const int mask = 1 << (5 - q);
        // RY
        float ore = __shfl_xor(re, mask);
        float oim = __shfl_xor(im, mask);
        const float sg = (lane & mask) ? st : -st;
        re = ct * re + sg * ore;
        im = ct * im + sg * oim;
        // RZ
        const float s2 = (lane & mask) ? sp : -sp;
        const float nre = re * cp - im * s2;
        const float nim = re * s2 + im * cp;
        re = nre; im = nim;
    }

    // ---- variational layers ----
    #pragma unroll
    for (int l = 0; l < NL; ++l) {
        #pragma unroll
        for (int q = 0; q < NQ; ++q) {
            const int mask = 1 << (5 - q);
            const float2 zz = *(const float2*)&T[24 * l + 4 * q];      // (cz,sz)
            const float2 yy = *(const float2*)&T[24 * l + 4 * q + 2];  // (cy,sy)
            // RZ
            const float sz = (lane & mask) ? zz.y : -zz.y;
            const float nre = re * zz.x - im * sz;
            const float nim = re * sz + im * zz.x;
            // RY
            const float ore = __shfl_xor(nre, mask);
            const float oim = __shfl_xor(nim, mask);
            const float sy = (lane & mask) ? yy.y : -yy.y;
            re = yy.x * nre + sy * ore;
            im = yy.x * nim + sy * oim;
        }
        // fused 6-CNOT block: one lane permutation
        re = __shfl(re, src);
        im = __shfl(im, src);
    }

    // ---- measurement: probs -> 6 Pauli-Z expectations via in-wave FWHT ----
    float v = re * re + im * im;
    #pragma unroll
    for (int m = 0; m < NQ; ++m) {
        const int mask = 1 << m;
        const float o = __shfl_xor(v, mask);
        v = (lane & mask) ? (o - v) : (v + o);
    }
    // lane e holds WHT[e]; exp_val[q] lives at lane (1 << (5-q)).
    if (__popc(lane) == 1) {
        const int bitpos = 31 - __clz(lane);
        const int q = 5 - bitpos;
        out[(size_t)b * NQ + q] = 1.f / (1.f + __expf(-v));
    }
}

extern "C" void kernel_launch(void* const* d_in, const int* in_sizes, int n_in,
                              void* d_out, int out_size, void* d_ws, size_t ws_size,
                              hipStream_t stream) {
    const float* x = (const float*)d_in[0];
    const float* w = (const float*)d_in[1];
    float* out = (float*)d_out;
    const int batch = in_sizes[0] / 3;  // B = 32768

    const int threads = 256;            // 4 waves/block
    const int waves_per_block = threads / 64;
    const int blocks = (batch + waves_per_block - 1) / waves_per_block;
    qsim_kernel<<<blocks, threads, 0, stream>>>(x, w, out, batch);
}

// Round 3
// 31.078 us; speedup vs baseline: 2.0298x; 1.6043x over previous
//
#include <hip/hip_runtime.h>

#define NQ 6
#define NL 6
#define TSTRIDE 148   // words per sample trig row: 36 gates * 4 + 4 pad -> conflict-free b128 reads

// 8 lanes per sample; lane group g = lane&7 holds amplitude bits k5k4k3 (qubits 0,1,2),
// register slot t (0..7) holds bits k2k1k0 (qubits 3,4,5). Amplitude k = g*8 + t.
// One wave = 8 samples. RZ is lane-local; RY on qubits 3-5 register-local;
// RY on qubits 0-2 via shfl_xor masks 4/2/1. CNOT block decomposed (2 renames free).
// Final CNOT block skipped; readout remapped to WHT indices {31,48,56,60,62,63}.
__global__ __launch_bounds__(256) void qsim_kernel(
    const float* __restrict__ x,
    const float* __restrict__ w,
    float* __restrict__ out,
    int batch)
{
    __shared__ float tbl[32 * TSTRIDE];
    __shared__ float outbuf[4][48];

    const int tid   = threadIdx.x;
    const int wavei = tid >> 6;          // wave in block 0..3
    const int lane  = tid & 63;
    const int sw    = lane >> 3;         // sample within wave 0..7
    const int g     = lane & 7;          // glane (amplitude bits 5..3)
    const int S     = tid >> 3;          // sample within block 0..31
    const int b     = blockIdx.x * 32 + S;
    if (b >= batch) return;              // exact for B=32768 (never divergent)

    float* T = &tbl[S * TSTRIDE];

    // ---- lane-parallel trig: 72 angles/sample, 9 per lane ----
    {
        const float* wp = w + (size_t)b * (2 * NQ * NL);
        #pragma unroll
        for (int j = 0; j < 9; ++j) {
            const int A = g * 9 + j;             // angle id 0..71
            const float a = wp[A];
            float s, c;
            __sincosf(a * 0.5f, &s, &c);
            const int word = (A >> 1) * 4 + (A & 1) * 2;  // gate*4 + {0:z,2:y}
            T[word]     = c;
            T[word + 1] = s;
        }
    }

    // ---- encode coefficients via half-angle identities ----
    const float x0 = x[b * 3 + 0];
    const float x1 = x[b * 3 + 1];
    const float x2 = x[b * 3 + 2];
    const float z  = fminf(1.f, fmaxf(-1.f, x2));
    const float ect = sqrtf(0.5f * (1.f + z));            // cos(theta/2)
    const float est = sqrtf(0.5f * (1.f - z));            // sin(theta/2)
    const float rr  = sqrtf(x0 * x0 + x1 * x1) + 1e-30f;
    const float cphi = x0 / rr;
    const float ecp = sqrtf(fmaxf(0.f, 0.5f * (1.f + cphi)));  // cos(phi/2)
    float esp       = sqrtf(fmaxf(0.f, 0.5f * (1.f - cphi)));  // |sin(phi/2)|
    esp = (x1 < 0.f) ? -esp : esp;

    // ---- state ----
    float re[8], im[8];
    #pragma unroll
    for (int t = 0; t < 8; ++t) { re[t] = 0.f; im[t] = 0.f; }
    re[0] = (g == 0) ? 1.f : 0.f;

    // ---- gate macros (q must be compile-time after unroll) ----
    #define APPLY_RY(q, c, s)                                              \
    do {                                                                   \
        if ((q) < 3) {                                                     \
            const int lm = 4 >> (q);                                       \
            const float sg = (lane & lm) ? (s) : -(s);                     \
            _Pragma("unroll")                                              \
            for (int t = 0; t < 8; ++t) {                                  \
                const float ore = __shfl_xor(re[t], lm);                   \
                const float oim = __shfl_xor(im[t], lm);                   \
                re[t] = (c) * re[t] + sg * ore;                            \
                im[t] = (c) * im[t] + sg * oim;                            \
            }                                                              \
        } else {                                                           \
            const int sb = 1 << (5 - (q));                                 \
            _Pragma("unroll")                                              \
            for (int t = 0; t < 8; ++t) {                                  \
                if (!(t & sb)) {                                           \
                    const int t1 = t | sb;                                 \
                    const float a0r = re[t],  a0i = im[t];                 \
                    const float a1r = re[t1], a1i = im[t1];                \
                    re[t]  = (c) * a0r - (s) * a1r;                        \
                    im[t]  = (c) * a0i - (s) * a1i;                        \
                    re[t1] = (s) * a0r + (c) * a1r;                        \
                    im[t1] = (s) * a0i + (c) * a1i;                        \
                }                                                          \
            }                                                              \
        }                                                                  \
    } while (0)

    #define APPLY_RZ(q, c, s)                                              \
    do {                                                                   \
        if ((q) < 3) {                                                     \
            const int lm = 4 >> (q);                                       \
            const float s2 = (lane & lm) ? (s) : -(s);                     \
            _Pragma("unroll")                                              \
            for (int t = 0; t < 8; ++t) {                                  \
                const float nr = re[t] * (c) - im[t] * s2;                 \
                im[t] = re[t] * s2 + im[t] * (c);                          \
                re[t] = nr;                                                \
            }                                                              \
        } else {                                                           \
            const int sb = 1 << (5 - (q));                                 \
            _Pragma("unroll")                                              \
            for (int t = 0; t < 8; ++t) {                                  \
                const float s2 = (t & sb) ? (s) : -(s);                    \
                const float nr = re[t] * (c) - im[t] * s2;                 \
                im[t] = re[t] * s2 + im[t] * (c);                          \
                re[t] = nr;                                                \
            }                                                              \
        }                                                                  \
    } while (0)

    // ---- encoding layer: per qubit RY(theta) then RZ(phi) ----
    #pragma unroll
    for (int q = 0; q < NQ; ++q) {
        APPLY_RY(q, ect, est);
        APPLY_RZ(q, ecp, esp);
    }

    // ---- fused lane permutation for CNOT(0,1) o CNOT(1,2): src_g = (g2, g1^g2, g0^g1) ----
    const int g2 = (g >> 2) & 1, g1 = (g >> 1) & 1, g0 = g & 1;
    const int srcLane = (lane & 56) | (g2 << 2) | ((g1 ^ g2) << 1) | (g0 ^ g1);

    // ---- layer gates (RZ then RY per qubit) ----
    auto layer_gates = [&](int l) {
        #pragma unroll
        for (int q = 0; q < NQ; ++q) {
            const float4 cf = *(const float4*)&T[(l * 6 + q) * 4];  // (cz,sz,cy,sy)
            APPLY_RZ(q, cf.x, cf.y);
            APPLY_RY(q, cf.z, cf.w);
        }
    };

    for (int l = 0; l < NL - 1; ++l) {
        layer_gates(l);
        // ---- CNOT block (layers 0..4) ----
        // 1) CNOT(0,1) o CNOT(1,2): lane permutation pull
        #pragma unroll
        for (int t = 0; t < 8; ++t) {
            re[t] = __shfl(re[t], srcLane);
            im[t] = __shfl(im[t], srcLane);
        }
        // 2) CNOT(2,3): lane bit0 controls slot swap t <-> t^4
        {
            const bool c23 = (lane & 1);
            #pragma unroll
            for (int t = 0; t < 4; ++t) {
                const int t1 = t + 4;
                const float ar = re[t], ai = im[t], br = re[t1], bi = im[t1];
                re[t]  = c23 ? br : ar;  im[t]  = c23 ? bi : ai;
                re[t1] = c23 ? ar : br;  im[t1] = c23 ? ai : bi;
            }
        }
        // 3) CNOT(3,4): rename swap (4,6),(5,7)  [free after regalloc]
        { float tr, ti;
          tr = re[4]; re[4] = re[6]; re[6] = tr;  ti = im[4]; im[4] = im[6]; im[6] = ti;
          tr = re[5]; re[5] = re[7]; re[7] = tr;  ti = im[5]; im[5] = im[7]; im[7] = ti; }
        // 4) CNOT(4,5): rename swap (2,3),(6,7)
        { float tr, ti;
          tr = re[2]; re[2] = re[3]; re[3] = tr;  ti = im[2]; im[2] = im[3]; im[3] = ti;
          tr = re[6]; re[6] = re[7]; re[7] = tr;  ti = im[6]; im[6] = im[7]; im[7] = ti; }
        // 5) CNOT(5,0): odd slots exchange across lane bit2 (mask 4)
        #pragma unroll
        for (int t = 1; t < 8; t += 2) {
            re[t] = __shfl_xor(re[t], 4);
            im[t] = __shfl_xor(im[t], 4);
        }
    }
    layer_gates(NL - 1);   // final layer: CNOT block folded into readout remap

    // ---- measurement: probs -> 8x8 FWHT (3 local + 3 lane stages) ----
    float v[8];
    #pragma unroll
    for (int t = 0; t < 8; ++t) v[t] = re[t] * re[t] + im[t] * im[t];
    #pragma unroll
    for (int mi = 0; mi < 3; ++mi) {
        const int m = 4 >> mi;    // 4,2,1 (slot bits)
        #pragma unroll
        for (int t = 0; t < 8; ++t) {
            if (!(t & m)) {
                const float a = v[t], bb = v[t | m];
                v[t] = a + bb;
                v[t | m] = a - bb;
            }
        }
    }
    #pragma unroll
    for (int mi = 0; mi < 3; ++mi) {
        const int mask = 1 << mi; // 1,2,4 (lane bits = amplitude bits 3,4,5)
        const float sgn = (lane & mask) ? -1.f : 1.f;
        #pragma unroll
        for (int t = 0; t < 8; ++t) {
            const float o = __shfl_xor(v[t], mask);
            v[t] = fmaf(sgn, v[t], o);
        }
    }
    // lane g, slot t holds WHT[g*8 + t]

    // ---- readout: skipped-CNOT remap -> WHT indices q0..q5 = {31,48,56,60,62,63} ----
    if (g == 3) outbuf[wavei][sw * 6 + 0] = v[7];   // e=31
    if (g == 6) outbuf[wavei][sw * 6 + 1] = v[0];   // e=48
    if (g == 7) {
        outbuf[wavei][sw * 6 + 2] = v[0];           // e=56
        outbuf[wavei][sw * 6 + 3] = v[4];           // e=60
        outbuf[wavei][sw * 6 + 4] = v[6];           // e=62
        outbuf[wavei][sw * 6 + 5] = v[7];           // e=63
    }
    if (lane < 48) {
        const float ev = outbuf[wavei][lane];
        const long long oidx = (long long)(blockIdx.x * 32 + wavei * 8) * 6 + lane;
        if (oidx < (long long)batch * 6)
            out[oidx] = 1.f / (1.f + __expf(-ev));
    }

    #undef APPLY_RY
    #undef APPLY_RZ
}

extern "C" void kernel_launch(void* const* d_in, const int* in_sizes, int n_in,
                              void* d_out, int out_size, void* d_ws, size_t ws_size,
                              hipStream_t stream) {
    const float* x = (const float*)d_in[0];
    const float* w = (const float*)d_in[1];
    float* out = (float*)d_out;
    const int batch = in_sizes[0] / 3;   // B = 32768

    const int threads = 256;             // 4 waves = 32 samples per block
    const int blocks = (batch + 31) / 32;
    qsim_kernel<<<blocks, threads, 0, stream>>>(x, w, out, batch);
}

// Round 5
// 30.017 us; speedup vs baseline: 2.1015x; 1.0353x over previous
//
#include <hip/hip_runtime.h>

#define NQ 6
#define NL 6
#define TSTRIDE 148   // words per sample trig row: 36 gates * 4 + 4 pad (rows spread banks)

// Layout (validated in R3): amplitude k = (b5<<5)|(b4<<4)|(b3<<3)|t
//   b5 <-> lane bit2, b4 <-> lane bit1, b3 <-> lane bit0   (g = lane & 7)
//   t (register slots 0..7) = amp bits 2..0
//   sample-within-wave sw = lane >> 3 (8 samples/wave)
// Qubit q <-> amp bit (5-q). Gate-path shuffles are pure-VALU DPP:
//   lane^1 = quad_perm 0xB1, lane^2 = quad_perm 0x4E,
//   lane^4 = ROW_HALF_MIRROR (lane^7) o quad_perm 0x1B (lane^3).

template<int CTRL>
__device__ __forceinline__ float dppf(float x) {
    return __builtin_bit_cast(float,
        __builtin_amdgcn_update_dpp(0, __builtin_bit_cast(int, x), CTRL, 0xF, 0xF, true));
}
__device__ __forceinline__ float sx1(float x) { return dppf<0xB1>(x); }              // lane^1
__device__ __forceinline__ float sx2(float x) { return dppf<0x4E>(x); }              // lane^2
__device__ __forceinline__ float sx4(float x) { return dppf<0x1B>(dppf<0x141>(x)); } // lane^4

template<int Q>
__device__ __forceinline__ float lshuf(float v) {
    if constexpr (Q == 0) return sx4(v);
    else if constexpr (Q == 1) return sx2(v);
    else return sx1(v);
}

template<int Q>
__device__ __forceinline__ void apply_rz(float (&re)[8], float (&im)[8],
                                         float c, float s, int lane) {
    if constexpr (Q < 3) {
        const int lm = 4 >> Q;
        const float s2 = (lane & lm) ? s : -s;
        #pragma unroll
        for (int t = 0; t < 8; ++t) {
            const float nr = fmaf(re[t], c, -(im[t] * s2));
            im[t] = fmaf(re[t], s2, im[t] * c);
            re[t] = nr;
        }
    } else {
        const int sb = 1 << (5 - Q);
        #pragma unroll
        for (int t = 0; t < 8; ++t) {
            const float s2 = (t & sb) ? s : -s;
            const float nr = fmaf(re[t], c, -(im[t] * s2));
            im[t] = fmaf(re[t], s2, im[t] * c);
            re[t] = nr;
        }
    }
}

template<int Q>
__device__ __forceinline__ void apply_ry(float (&re)[8], float (&im)[8],
                                         float c, float s, int lane) {
    if constexpr (Q < 3) {
        const int lm = 4 >> Q;
        const float sg = (lane & lm) ? s : -s;
        #pragma unroll
        for (int t = 0; t < 8; ++t) {
            const float ore = lshuf<Q>(re[t]);
            const float oim = lshuf<Q>(im[t]);
            re[t] = fmaf(c, re[t], sg * ore);
            im[t] = fmaf(c, im[t], sg * oim);
        }
    } else {
        const int sb = 1 << (5 - Q);
        #pragma unroll
        for (int t = 0; t < 8; ++t) {
            if (!(t & sb)) {
                const int t1 = t | sb;
                const float a0r = re[t],  a0i = im[t];
                const float a1r = re[t1], a1i = im[t1];
                re[t]  = fmaf(c, a0r, -(s * a1r));
                im[t]  = fmaf(c, a0i, -(s * a1i));
                re[t1] = fmaf(s, a0r, c * a1r);
                im[t1] = fmaf(s, a0i, c * a1i);
            }
        }
    }
}

__global__ __launch_bounds__(256) void qsim_kernel(
    const float* __restrict__ x,
    const float* __restrict__ w,
    float* __restrict__ out,
    int batch)
{
    __shared__ float tbl[32 * TSTRIDE];
    __shared__ float outbuf[4][48];

    const int tid   = threadIdx.x;
    const int wavei = tid >> 6;
    const int lane  = tid & 63;
    const int sw    = lane >> 3;          // sample within wave 0..7
    const int g     = lane & 7;           // amp bits 5..3
    const int S     = tid >> 3;           // sample within block 0..31
    const int b     = blockIdx.x * 32 + S;
    if (b >= batch) return;               // exact for B=32768 (never divergent)

    float* T = &tbl[S * TSTRIDE];

    // ---- lane-parallel trig: 72 angles/sample, 9 per lane (R3-validated) ----
    {
        const float* wp = w + (size_t)b * (2 * NQ * NL);
        #pragma unroll
        for (int j = 0; j < 9; ++j) {
            const int A = g * 9 + j;                      // angle id 0..71
            float s, c;
            __sincosf(wp[A] * 0.5f, &s, &c);
            const int word = (A >> 1) * 4 + (A & 1) * 2;  // gate*4 + {0:z,2:y}
            T[word]     = c;
            T[word + 1] = s;
        }
    }

    // ---- encode: product state amp[k] = A^(6-popc(k)) * B^popc(k) ----
    const float x0 = x[b * 3 + 0];
    const float x1 = x[b * 3 + 1];
    const float x2 = x[b * 3 + 2];
    const float z  = fminf(1.f, fmaxf(-1.f, x2));
    const float ct = sqrtf(0.5f * (1.f + z));             // cos(theta/2)
    const float st = sqrtf(0.5f * (1.f - z));             // sin(theta/2)
    const float rr = sqrtf(x0 * x0 + x1 * x1) + 1e-30f;
    const float cphi = x0 / rr;
    const float cp = sqrtf(fmaxf(0.f, 0.5f * (1.f + cphi)));
    float sp       = sqrtf(fmaxf(0.f, 0.5f * (1.f - cphi)));
    sp = (x1 < 0.f) ? -sp : sp;   // 2pi wrap & sign = global phase, cancels in |psi|^2

    const float Ar = ct * cp, Ai = -ct * sp;   // qubit |0> component
    const float Br = st * cp, Bi =  st * sp;   // qubit |1> component

    float pr[7], pi_[7], qr[7], qi[7];
    pr[0] = 1.f; pi_[0] = 0.f; qr[0] = 1.f; qi[0] = 0.f;
    pr[1] = Ar;  pi_[1] = Ai;  qr[1] = Br;  qi[1] = Bi;
    #pragma unroll
    for (int p = 2; p <= 6; ++p) {
        pr[p]  = fmaf(pr[p-1], Ar, -(pi_[p-1] * Ai));
        pi_[p] = fmaf(pr[p-1], Ai,  pi_[p-1] * Ar);
        qr[p]  = fmaf(qr[p-1], Br, -(qi[p-1] * Bi));
        qi[p]  = fmaf(qr[p-1], Bi,  qi[p-1] * Br);
    }
    float cr[7], ci[7];                        // c[p] = A^(6-p) B^p
    #pragma unroll
    for (int p = 0; p <= 6; ++p) {
        cr[p] = fmaf(pr[6-p], qr[p], -(pi_[6-p] * qi[p]));
        ci[p] = fmaf(pr[6-p], qi[p],  pi_[6-p] * qr[p]);
    }
    // lane-held popcount pg = popc(g); select u[j] = c[pg+j], j=0..3
    const int  pg = __popc(g);
    const bool p0 = (pg & 1) != 0, p1 = (pg & 2) != 0;
    float ur[4], ui[4];
    #pragma unroll
    for (int j = 0; j < 4; ++j) {
        const float lr  = p0 ? cr[j+1] : cr[j];
        const float li  = p0 ? ci[j+1] : ci[j];
        const float hr2 = p0 ? cr[j+3] : cr[j+2];
        const float hi2 = p0 ? ci[j+3] : ci[j+2];
        ur[j] = p1 ? hr2 : lr;
        ui[j] = p1 ? hi2 : li;
    }
    float re[8], im[8];                        // popc(t) = 0,1,1,2,1,2,2,3
    re[0]=ur[0]; im[0]=ui[0];  re[1]=ur[1]; im[1]=ui[1];
    re[2]=ur[1]; im[2]=ui[1];  re[3]=ur[2]; im[3]=ui[2];
    re[4]=ur[1]; im[4]=ui[1];  re[5]=ur[2]; im[5]=ui[2];
    re[6]=ur[2]; im[6]=ui[2];  re[7]=ur[3]; im[7]=ui[3];

    // ---- variational layers ----
    for (int l = 0; l < NL; ++l) {
        const float4 c0 = *(const float4*)&T[l*24 +  0];
        const float4 c1 = *(const float4*)&T[l*24 +  4];
        const float4 c2 = *(const float4*)&T[l*24 +  8];
        const float4 c3 = *(const float4*)&T[l*24 + 12];
        const float4 c4 = *(const float4*)&T[l*24 + 16];
        const float4 c5 = *(const float4*)&T[l*24 + 20];
        apply_rz<0>(re, im, c0.x, c0.y, lane);  apply_ry<0>(re, im, c0.z, c0.w, lane);
        apply_rz<1>(re, im, c1.x, c1.y, lane);  apply_ry<1>(re, im, c1.z, c1.w, lane);
        apply_rz<2>(re, im, c2.x, c2.y, lane);  apply_ry<2>(re, im, c2.z, c2.w, lane);
        apply_rz<3>(re, im, c3.x, c3.y, lane);  apply_ry<3>(re, im, c3.z, c3.w, lane);
        apply_rz<4>(re, im, c4.x, c4.y, lane);  apply_ry<4>(re, im, c4.z, c4.w, lane);
        apply_rz<5>(re, im, c5.x, c5.y, lane);  apply_ry<5>(re, im, c5.z, c5.w, lane);

        if (l < NL - 1) {
            // CNOT(0,1): ctrl amp b5 (lane&4), tgt amp b4 (lane^2)
            const bool c01 = (lane & 4) != 0;
            #pragma unroll
            for (int t = 0; t < 8; ++t) {
                const float dr = sx2(re[t]), di = sx2(im[t]);
                re[t] = c01 ? dr : re[t];
                im[t] = c01 ? di : im[t];
            }
            // CNOT(1,2): ctrl amp b4 (lane&2), tgt amp b3 (lane^1)
            const bool c12 = (lane & 2) != 0;
            #pragma unroll
            for (int t = 0; t < 8; ++t) {
                const float dr = sx1(re[t]), di = sx1(im[t]);
                re[t] = c12 ? dr : re[t];
                im[t] = c12 ? di : im[t];
            }
            // CNOT(2,3): ctrl amp b3 (lane&1), tgt slot bit2: swap t <-> t^4
            const bool c23 = (lane & 1) != 0;
            #pragma unroll
            for (int t = 0; t < 4; ++t) {
                const int t1 = t + 4;
                const float ar = re[t], ai = im[t], br = re[t1], bi = im[t1];
                re[t]  = c23 ? br : ar;  im[t]  = c23 ? bi : ai;
                re[t1] = c23 ? ar : br;  im[t1] = c23 ? ai : bi;
            }
            // CNOT(3,4): slot rename (4,6),(5,7)
            { float tr, ti;
              tr=re[4]; re[4]=re[6]; re[6]=tr;  ti=im[4]; im[4]=im[6]; im[6]=ti;
              tr=re[5]; re[5]=re[7]; re[7]=tr;  ti=im[5]; im[5]=im[7]; im[7]=ti; }
            // CNOT(4,5): slot rename (2,3),(6,7)
            { float tr, ti;
              tr=re[2]; re[2]=re[3]; re[3]=tr;  ti=im[2]; im[2]=im[3]; im[3]=ti;
              tr=re[6]; re[6]=re[7]; re[7]=tr;  ti=im[6]; im[6]=im[7]; im[7]=ti; }
            // CNOT(5,0): ctrl slot bit0 (odd t), tgt amp b5: lane^4
            #pragma unroll
            for (int t = 1; t < 8; t += 2) {
                re[t] = sx4(re[t]);
                im[t] = sx4(im[t]);
            }
        }
    }
    // final CNOT block folded into readout (WHT indices {31,48,56,60,62,63})

    // ---- probs -> FWHT (3 slot stages + 3 lane stages, all VALU) ----
    float v[8];
    #pragma unroll
    for (int t = 0; t < 8; ++t) v[t] = fmaf(re[t], re[t], im[t] * im[t]);
    #pragma unroll
    for (int mi = 0; mi < 3; ++mi) {
        const int m = 4 >> mi;
        #pragma unroll
        for (int t = 0; t < 8; ++t) {
            if (!(t & m)) {
                const float a2 = v[t], b2 = v[t | m];
                v[t] = a2 + b2;
                v[t | m] = a2 - b2;
            }
        }
    }
    {   // amp bit3 <-> lane bit0
        const float sg = (lane & 1) ? -1.f : 1.f;
        #pragma unroll
        for (int t = 0; t < 8; ++t) { const float o = sx1(v[t]); v[t] = fmaf(sg, v[t], o); }
    }
    {   // amp bit4 <-> lane bit1
        const float sg = (lane & 2) ? -1.f : 1.f;
        #pragma unroll
        for (int t = 0; t < 8; ++t) { const float o = sx2(v[t]); v[t] = fmaf(sg, v[t], o); }
    }
    {   // amp bit5 <-> lane bit2
        const float sg = (lane & 4) ? -1.f : 1.f;
        #pragma unroll
        for (int t = 0; t < 8; ++t) { const float o = sx4(v[t]); v[t] = fmaf(sg, v[t], o); }
    }
    // lane g, slot t holds WHT[g*8 + t]

    // ---- readout (skipped final-CNOT remap, R3-validated) ----
    if (g == 3) outbuf[wavei][sw * 6 + 0] = v[7];   // e=31
    if (g == 6) outbuf[wavei][sw * 6 + 1] = v[0];   // e=48
    if (g == 7) {
        outbuf[wavei][sw * 6 + 2] = v[0];           // e=56
        outbuf[wavei][sw * 6 + 3] = v[4];           // e=60
        outbuf[wavei][sw * 6 + 4] = v[6];           // e=62
        outbuf[wavei][sw * 6 + 5] = v[7];           // e=63
    }
    if (lane < 48) {
        const float ev = outbuf[wavei][lane];
        const long long oidx = (long long)(blockIdx.x * 32 + wavei * 8) * 6 + lane;
        if (oidx < (long long)batch * 6)
            out[oidx] = 1.f / (1.f + __expf(-ev));
    }
}

extern "C" void kernel_launch(void* const* d_in, const int* in_sizes, int n_in,
                              void* d_out, int out_size, void* d_ws, size_t ws_size,
                              hipStream_t stream) {
    const float* x = (const float*)d_in[0];
    const float* w = (const float*)d_in[1];
    float* out = (float*)d_out;
    const int batch = in_sizes[0] / 3;   // B = 32768

    const int threads = 256;             // 4 waves = 32 samples per block
    const int blocks = (batch + 31) / 32;
    qsim_kernel<<<blocks, threads, 0, stream>>>(x, w, out, batch);
}

// Round 6
// 26.225 us; speedup vs baseline: 2.4054x; 1.1446x over previous
//
#include <hip/hip_runtime.h>

#define NQ 6
#define NL 6
#define TSTRIDE 148   // words per sample trig row: 36 gates * 4 + 4 pad (conflict-free b128)

// Layout (validated R3/R5): amplitude k = (b5<<5)|(b4<<4)|(b3<<3)|t, t = 2p + h
//   b5 <-> lane bit2, b4 <-> lane bit1, b3 <-> lane bit0   (g = lane & 7)
//   p = float2 pair index (amp bits 2,1), h = .x/.y half (amp bit 0)
//   sample-within-wave sw = lane >> 3 (8 samples/wave)
// Qubit q <-> amp bit (5-q). Lane shuffles are pure-VALU DPP:
//   lane^1 = quad_perm 0xB1, lane^2 = quad_perm 0x4E,
//   lane^4 = ROW_HALF_MIRROR (0x141, lane^7) o quad_perm 0x1B (lane^3).
// R6: state packed as v2f[4]; math uses v_pk_fma_f32-class packed FP32.

typedef float v2f __attribute__((ext_vector_type(2)));

template<int CTRL>
__device__ __forceinline__ float dppf(float x) {
    return __builtin_bit_cast(float,
        __builtin_amdgcn_update_dpp(0, __builtin_bit_cast(int, x), CTRL, 0xF, 0xF, true));
}
__device__ __forceinline__ float sx1(float x) { return dppf<0xB1>(x); }              // lane^1
__device__ __forceinline__ float sx2(float x) { return dppf<0x4E>(x); }              // lane^2
__device__ __forceinline__ float sx4(float x) { return dppf<0x1B>(dppf<0x141>(x)); } // lane^4

__device__ __forceinline__ v2f fma2(v2f a, v2f b, v2f c) {
    return __builtin_elementwise_fma(a, b, c);
}
__device__ __forceinline__ v2f swap2(v2f a) { return __builtin_shufflevector(a, a, 1, 0); }

__device__ __forceinline__ v2f shuf2_1(v2f a) { return v2f{sx1(a.x), sx1(a.y)}; }
__device__ __forceinline__ v2f shuf2_2(v2f a) { return v2f{sx2(a.x), sx2(a.y)}; }
__device__ __forceinline__ v2f shuf2_4(v2f a) { return v2f{sx4(a.x), sx4(a.y)}; }

template<int Q>
__device__ __forceinline__ void rz2(v2f (&re)[4], v2f (&im)[4], float c, float s, int lane) {
    const v2f C = {c, c};
    if constexpr (Q < 3) {
        const int lm = 4 >> Q;
        const float s2 = (lane & lm) ? s : -s;
        const v2f S = {s2, s2};
        #pragma unroll
        for (int p = 0; p < 4; ++p) {
            const v2f nr = fma2(re[p], C, -(im[p] * S));
            im[p] = fma2(re[p], S, im[p] * C);
            re[p] = nr;
        }
    } else if constexpr (Q == 5) {
        const v2f S = {-s, s};          // sign by h (amp bit0)
        #pragma unroll
        for (int p = 0; p < 4; ++p) {
            const v2f nr = fma2(re[p], C, -(im[p] * S));
            im[p] = fma2(re[p], S, im[p] * C);
            re[p] = nr;
        }
    } else {
        const v2f Sn = {-s, -s}, Sp = {s, s};
        #pragma unroll
        for (int p = 0; p < 4; ++p) {
            const v2f S = (((Q == 3) ? (p & 2) : (p & 1)) != 0) ? Sp : Sn;
            const v2f nr = fma2(re[p], C, -(im[p] * S));
            im[p] = fma2(re[p], S, im[p] * C);
            re[p] = nr;
        }
    }
}

template<int Q>
__device__ __forceinline__ void ry2(v2f (&re)[4], v2f (&im)[4], float c, float s, int lane) {
    const v2f C = {c, c};
    if constexpr (Q < 3) {
        const int lm = 4 >> Q;
        const float sg = (lane & lm) ? s : -s;
        const v2f SG = {sg, sg};
        #pragma unroll
        for (int p = 0; p < 4; ++p) {
            v2f ore, oim;
            if constexpr (Q == 0)      { ore = shuf2_4(re[p]); oim = shuf2_4(im[p]); }
            else if constexpr (Q == 1) { ore = shuf2_2(re[p]); oim = shuf2_2(im[p]); }
            else                       { ore = shuf2_1(re[p]); oim = shuf2_1(im[p]); }
            re[p] = fma2(C, re[p], SG * ore);
            im[p] = fma2(C, im[p], SG * oim);
        }
    } else if constexpr (Q == 3) {      // amp bit2: pairs (p, p+2)
        const v2f S = {s, s};
        #pragma unroll
        for (int p = 0; p < 2; ++p) {
            const v2f a0r = re[p], a0i = im[p], a1r = re[p+2], a1i = im[p+2];
            re[p]   = fma2(C, a0r, -(S * a1r));
            im[p]   = fma2(C, a0i, -(S * a1i));
            re[p+2] = fma2(S, a0r, C * a1r);
            im[p+2] = fma2(S, a0i, C * a1i);
        }
    } else if constexpr (Q == 4) {      // amp bit1: pairs (p, p+1), p in {0,2}
        const v2f S = {s, s};
        #pragma unroll
        for (int p = 0; p < 4; p += 2) {
            const v2f a0r = re[p], a0i = im[p], a1r = re[p+1], a1i = im[p+1];
            re[p]   = fma2(C, a0r, -(S * a1r));
            im[p]   = fma2(C, a0i, -(S * a1i));
            re[p+1] = fma2(S, a0r, C * a1r);
            im[p+1] = fma2(S, a0i, C * a1i);
        }
    } else {                            // Q == 5: within-pair butterfly
        const v2f SM = {-s, s};
        #pragma unroll
        for (int p = 0; p < 4; ++p) {
            re[p] = fma2(C, re[p], SM * swap2(re[p]));
            im[p] = fma2(C, im[p], SM * swap2(im[p]));
        }
    }
}

__device__ __forceinline__ void cnot_block(v2f (&re)[4], v2f (&im)[4], int lane) {
    // CNOT(0,1): ctrl amp b5 (lane&4), tgt amp b4 (lane^2)
    const bool c01 = (lane & 4) != 0;
    #pragma unroll
    for (int p = 0; p < 4; ++p) {
        const v2f dr = shuf2_2(re[p]), di = shuf2_2(im[p]);
        re[p] = c01 ? dr : re[p];
        im[p] = c01 ? di : im[p];
    }
    // CNOT(1,2): ctrl amp b4 (lane&2), tgt amp b3 (lane^1)
    const bool c12 = (lane & 2) != 0;
    #pragma unroll
    for (int p = 0; p < 4; ++p) {
        const v2f dr = shuf2_1(re[p]), di = shuf2_1(im[p]);
        re[p] = c12 ? dr : re[p];
        im[p] = c12 ? di : im[p];
    }
    // CNOT(2,3): ctrl amp b3 (lane&1), tgt amp b2: p <-> p+2
    const bool c23 = (lane & 1) != 0;
    #pragma unroll
    for (int p = 0; p < 2; ++p) {
        const v2f ar = re[p], ai = im[p], br = re[p+2], bi = im[p+2];
        re[p]   = c23 ? br : ar;  im[p]   = c23 ? bi : ai;
        re[p+2] = c23 ? ar : br;  im[p+2] = c23 ? ai : bi;
    }
    // CNOT(3,4): swap p2 <-> p3 (register rename, free)
    { v2f t;
      t = re[2]; re[2] = re[3]; re[3] = t;
      t = im[2]; im[2] = im[3]; im[3] = t; }
    // CNOT(4,5): within-pair swap on p = 1, 3
    re[1] = swap2(re[1]); im[1] = swap2(im[1]);
    re[3] = swap2(re[3]); im[3] = swap2(im[3]);
    // CNOT(5,0): ctrl amp b0 (h=1 -> .y), tgt amp b5: lane^4 on .y only
    #pragma unroll
    for (int p = 0; p < 4; ++p) {
        re[p].y = sx4(re[p].y);
        im[p].y = sx4(im[p].y);
    }
}

__global__ __launch_bounds__(256) void qsim_kernel(
    const float* __restrict__ x,
    const float* __restrict__ w,
    float* __restrict__ out,
    int batch)
{
    __shared__ float tbl[32 * TSTRIDE];
    __shared__ float outbuf[4][48];

    const int tid   = threadIdx.x;
    const int wavei = tid >> 6;
    const int lane  = tid & 63;
    const int sw    = lane >> 3;          // sample within wave 0..7
    const int g     = lane & 7;           // amp bits 5..3
    const int S     = tid >> 3;           // sample within block 0..31
    const int b     = blockIdx.x * 32 + S;
    if (b >= batch) return;               // exact for B=32768 (never divergent)

    float* T = &tbl[S * TSTRIDE];

    // ---- lane-parallel trig: 72 angles/sample, 9 per lane (validated) ----
    {
        const float* wp = w + (size_t)b * (2 * NQ * NL);
        #pragma unroll
        for (int j = 0; j < 9; ++j) {
            const int A = g * 9 + j;                      // angle id 0..71
            float s, c;
            __sincosf(wp[A] * 0.5f, &s, &c);
            const int word = (A >> 1) * 4 + (A & 1) * 2;  // gate*4 + {0:z,2:y}
            T[word]     = c;
            T[word + 1] = s;
        }
    }

    // ---- encode: product state amp[k] = A^(6-popc(k)) * B^popc(k) ----
    const float x0 = x[b * 3 + 0];
    const float x1 = x[b * 3 + 1];
    const float x2 = x[b * 3 + 2];
    const float z  = fminf(1.f, fmaxf(-1.f, x2));
    const float ct = sqrtf(0.5f * (1.f + z));
    const float st = sqrtf(0.5f * (1.f - z));
    const float rr = sqrtf(x0 * x0 + x1 * x1) + 1e-30f;
    const float cphi = x0 / rr;
    const float cp = sqrtf(fmaxf(0.f, 0.5f * (1.f + cphi)));
    float sp       = sqrtf(fmaxf(0.f, 0.5f * (1.f - cphi)));
    sp = (x1 < 0.f) ? -sp : sp;   // 2pi wrap & sign = global phase, cancels

    const float Ar = ct * cp, Ai = -ct * sp;
    const float Br = st * cp, Bi =  st * sp;

    float pr[7], pi_[7], qr[7], qi[7];
    pr[0] = 1.f; pi_[0] = 0.f; qr[0] = 1.f; qi[0] = 0.f;
    pr[1] = Ar;  pi_[1] = Ai;  qr[1] = Br;  qi[1] = Bi;
    #pragma unroll
    for (int p = 2; p <= 6; ++p) {
        pr[p]  = fmaf(pr[p-1], Ar, -(pi_[p-1] * Ai));
        pi_[p] = fmaf(pr[p-1], Ai,  pi_[p-1] * Ar);
        qr[p]  = fmaf(qr[p-1], Br, -(qi[p-1] * Bi));
        qi[p]  = fmaf(qr[p-1], Bi,  qi[p-1] * Br);
    }
    float cr[7], ci[7];
    #pragma unroll
    for (int p = 0; p <= 6; ++p) {
        cr[p] = fmaf(pr[6-p], qr[p], -(pi_[6-p] * qi[p]));
        ci[p] = fmaf(pr[6-p], qi[p],  pi_[6-p] * qr[p]);
    }
    const int  pg = __popc(g);
    const bool pb0 = (pg & 1) != 0, pb1 = (pg & 2) != 0;
    float ur[4], ui[4];
    #pragma unroll
    for (int j = 0; j < 4; ++j) {
        const float lr  = pb0 ? cr[j+1] : cr[j];
        const float li  = pb0 ? ci[j+1] : ci[j];
        const float hr2 = pb0 ? cr[j+3] : cr[j+2];
        const float hi2 = pb0 ? ci[j+3] : ci[j+2];
        ur[j] = pb1 ? hr2 : lr;
        ui[j] = pb1 ? hi2 : li;
    }
    // popc(t) over t=0..7 is 0,1,1,2,1,2,2,3 -> pack into pairs
    v2f re[4], im[4];
    re[0] = v2f{ur[0], ur[1]};  im[0] = v2f{ui[0], ui[1]};
    re[1] = v2f{ur[1], ur[2]};  im[1] = v2f{ui[1], ui[2]};
    re[2] = v2f{ur[1], ur[2]};  im[2] = v2f{ui[1], ui[2]};
    re[3] = v2f{ur[2], ur[3]};  im[3] = v2f{ui[2], ui[3]};

    // ---- variational layers ----
    for (int l = 0; l < NL - 1; ++l) {
        const float4 c0 = *(const float4*)&T[l*24 +  0];
        const float4 c1 = *(const float4*)&T[l*24 +  4];
        const float4 c2 = *(const float4*)&T[l*24 +  8];
        const float4 c3 = *(const float4*)&T[l*24 + 12];
        const float4 c4 = *(const float4*)&T[l*24 + 16];
        const float4 c5 = *(const float4*)&T[l*24 + 20];
        rz2<0>(re, im, c0.x, c0.y, lane);  ry2<0>(re, im, c0.z, c0.w, lane);
        rz2<1>(re, im, c1.x, c1.y, lane);  ry2<1>(re, im, c1.z, c1.w, lane);
        rz2<2>(re, im, c2.x, c2.y, lane);  ry2<2>(re, im, c2.z, c2.w, lane);
        rz2<3>(re, im, c3.x, c3.y, lane);  ry2<3>(re, im, c3.z, c3.w, lane);
        rz2<4>(re, im, c4.x, c4.y, lane);  ry2<4>(re, im, c4.z, c4.w, lane);
        rz2<5>(re, im, c5.x, c5.y, lane);  ry2<5>(re, im, c5.z, c5.w, lane);
        cnot_block(re, im, lane);
    }
    {   // final layer: CNOT block folded into readout remap
        const int l = NL - 1;
        const float4 c0 = *(const float4*)&T[l*24 +  0];
        const float4 c1 = *(const float4*)&T[l*24 +  4];
        const float4 c2 = *(const float4*)&T[l*24 +  8];
        const float4 c3 = *(const float4*)&T[l*24 + 12];
        const float4 c4 = *(const float4*)&T[l*24 + 16];
        const float4 c5 = *(const float4*)&T[l*24 + 20];
        rz2<0>(re, im, c0.x, c0.y, lane);  ry2<0>(re, im, c0.z, c0.w, lane);
        rz2<1>(re, im, c1.x, c1.y, lane);  ry2<1>(re, im, c1.z, c1.w, lane);
        rz2<2>(re, im, c2.x, c2.y, lane);  ry2<2>(re, im, c2.z, c2.w, lane);
        rz2<3>(re, im, c3.x, c3.y, lane);  ry2<3>(re, im, c3.z, c3.w, lane);
        rz2<4>(re, im, c4.x, c4.y, lane);  ry2<4>(re, im, c4.z, c4.w, lane);
        rz2<5>(re, im, c5.x, c5.y, lane);  ry2<5>(re, im, c5.z, c5.w, lane);
    }

    // ---- probs -> FWHT (3 packed slot stages + 3 lane stages) ----
    v2f v[4];
    #pragma unroll
    for (int p = 0; p < 4; ++p) v[p] = fma2(re[p], re[p], im[p] * im[p]);
    {   // amp bit2 stage: p <-> p+2
        v2f a, bb;
        a = v[0]; bb = v[2]; v[0] = a + bb; v[2] = a - bb;
        a = v[1]; bb = v[3]; v[1] = a + bb; v[3] = a - bb;
    }
    {   // amp bit1 stage: p <-> p+1
        v2f a, bb;
        a = v[0]; bb = v[1]; v[0] = a + bb; v[1] = a - bb;
        a = v[2]; bb = v[3]; v[2] = a + bb; v[3] = a - bb;
    }
    {   // amp bit0 stage: within pair
        const v2f PM = {1.f, -1.f};
        #pragma unroll
        for (int p = 0; p < 4; ++p) v[p] = fma2(PM, v[p], swap2(v[p]));
    }
    {   // amp bit3 <-> lane bit0
        const float sg = (lane & 1) ? -1.f : 1.f;
        const v2f SG = {sg, sg};
        #pragma unroll
        for (int p = 0; p < 4; ++p) v[p] = fma2(SG, v[p], shuf2_1(v[p]));
    }
    {   // amp bit4 <-> lane bit1
        const float sg = (lane & 2) ? -1.f : 1.f;
        const v2f SG = {sg, sg};
        #pragma unroll
        for (int p = 0; p < 4; ++p) v[p] = fma2(SG, v[p], shuf2_2(v[p]));
    }
    {   // amp bit5 <-> lane bit2
        const float sg = (lane & 4) ? -1.f : 1.f;
        const v2f SG = {sg, sg};
        #pragma unroll
        for (int p = 0; p < 4; ++p) v[p] = fma2(SG, v[p], shuf2_4(v[p]));
    }
    // lane g, pair p, half h holds WHT[g*8 + 2p + h]

    // ---- readout (skipped final-CNOT remap, validated): e = {31,48,56,60,62,63} ----
    if (g == 3) outbuf[wavei][sw * 6 + 0] = v[3].y;   // e=31
    if (g == 6) outbuf[wavei][sw * 6 + 1] = v[0].x;   // e=48
    if (g == 7) {
        outbuf[wavei][sw * 6 + 2] = v[0].x;           // e=56
        outbuf[wavei][sw * 6 + 3] = v[2].x;           // e=60
        outbuf[wavei][sw * 6 + 4] = v[3].x;           // e=62
        outbuf[wavei][sw * 6 + 5] = v[3].y;           // e=63
    }
    if (lane < 48) {
        const float ev = outbuf[wavei][lane];
        const long long oidx = (long long)(blockIdx.x * 32 + wavei * 8) * 6 + lane;
        if (oidx < (long long)batch * 6)
            out[oidx] = 1.f / (1.f + __expf(-ev));
    }
}

extern "C" void kernel_launch(void* const* d_in, const int* in_sizes, int n_in,
                              void* d_out, int out_size, void* d_ws, size_t ws_size,
                              hipStream_t stream) {
    const float* x = (const float*)d_in[0];
    const float* w = (const float*)d_in[1];
    float* out = (float*)d_out;
    const int batch = in_sizes[0] / 3;   // B = 32768

    const int threads = 256;             // 4 waves = 32 samples per block
    const int blocks = (batch + 31) / 32;
    qsim_kernel<<<blocks, threads, 0, stream>>>(x, w, out, batch);
}